// Round 1
// baseline (163.687 us; speedup 1.0000x reference)
//
#include <hip/hip_runtime.h>

// SparseConv1D on MI355X, round 0.
// out[b,o,l] = sum_{t,i} W[o,i,t] * x[b,i,l+tap_t]  (zero outside [0,L))
// Restructured as 32 shifted GEMMs: out[o,l] += (W_t . X)[o, l+tap_t]
// Prep: Xp = bf16, transposed [b][lp][i], lp in [0,4864) with 512 low / 256 high zero pad.
//       Wt = bf16, [t][o][i].
// Main: MFMA 16x16x32 bf16, wave tile 64(o) x 32(l), frags straight from global (L2-resident).

#define B_    16
#define CIN   64
#define COUT  64
#define LEN   4096
#define PAD_LO 512
#define PAD_HI 256
#define LPAD  (LEN + PAD_LO + PAD_HI)   // 4864
#define NTAP  32

typedef float f32x4 __attribute__((ext_vector_type(4)));
typedef short bf16x8_s __attribute__((ext_vector_type(8)));   // 8 bf16 as raw shorts
typedef __bf16 bf16x8_b __attribute__((ext_vector_type(8)));  // 8 bf16 as __bf16

// SFINAE shim: some toolchains type the gfx950 bf16 MFMA builtin with short
// vectors (V8s), others with __bf16 vectors (V8y). Exactly one overload is viable.
template <typename V>
static __device__ inline auto mfma_16x16x32_bf16(V a, V b, f32x4 c, int)
    -> decltype(__builtin_amdgcn_mfma_f32_16x16x32_bf16(a, b, c, 0, 0, 0)) {
  return __builtin_amdgcn_mfma_f32_16x16x32_bf16(a, b, c, 0, 0, 0);
}
template <typename V>
static __device__ inline f32x4 mfma_16x16x32_bf16(V a, V b, f32x4 c, long) {
  return __builtin_amdgcn_mfma_f32_16x16x32_bf16(
      __builtin_bit_cast(bf16x8_b, a), __builtin_bit_cast(bf16x8_b, b), c, 0, 0, 0);
}

static __device__ inline unsigned short f32_to_bf16_rne(float f) {
  unsigned int u = __builtin_bit_cast(unsigned int, f);
  u += 0x7fffu + ((u >> 16) & 1u);
  return (unsigned short)(u >> 16);
}

// ---------------- prep: x[b][i][l] fp32 -> Xp[b][lp][i] bf16 (padded) -------------
__global__ __launch_bounds__(256) void prep_x(const float* __restrict__ x,
                                              unsigned short* __restrict__ xp) {
  __shared__ float tile[64][65];
  const int b = blockIdx.y;
  const int lp0 = blockIdx.x * 64;           // tile over padded rows [0,4864)
  const int tid = threadIdx.x;
  const bool data = (lp0 >= PAD_LO) && (lp0 < PAD_LO + LEN);  // tile boundaries align with pad (512,4608 are multiples of 64)
  if (data) {
    const int l0 = lp0 - PAD_LO;
    for (int p = tid; p < 64 * 64; p += 256) {
      const int il = p >> 6, ll = p & 63;    // consecutive tid -> consecutive l (coalesced read)
      tile[ll][il] = x[(size_t)(b * CIN + il) * LEN + l0 + ll];
    }
  }
  __syncthreads();
  for (int p = tid; p < 64 * 64; p += 256) {
    const int ll = p >> 6, il = p & 63;      // consecutive tid -> consecutive i (coalesced write)
    const float v = data ? tile[ll][il] : 0.0f;
    xp[(size_t)(b * LPAD + lp0 + ll) * CIN + il] = f32_to_bf16_rne(v);
  }
}

// ---------------- prep: w[o][i][t] fp32 -> Wt[t][o][i] bf16 ----------------------
__global__ __launch_bounds__(256) void prep_w(const float* __restrict__ w,
                                              unsigned short* __restrict__ wt) {
  const int e = blockIdx.x * 256 + threadIdx.x;  // < 32*64*64 = 131072
  const int t = e >> 12;
  const int rem = e & 4095;
  const int o = rem >> 6, i = rem & 63;
  wt[e] = f32_to_bf16_rne(w[(size_t)(o * CIN + i) * NTAP + t]);
}

// ---------------- main: 32 shifted GEMMs, MFMA 16x16x32 bf16 ---------------------
__global__ __launch_bounds__(256) void sconv_main(const unsigned short* __restrict__ xp,
                                                  const unsigned short* __restrict__ wt,
                                                  float* __restrict__ out) {
  constexpr int TAP[NTAP] = {-512, -256, -128, -96, -64, -48, -32, -24, -16, -12, -8,
                             -6,   -4,   -3,   -2,  -1,  0,   1,   2,   3,   4,  6,
                             8,    12,   16,   24,  32,  48,  64,  96,  128, 256};
  const int b = blockIdx.y;
  const int wave = threadIdx.x >> 6;
  const int lane = threadIdx.x & 63;
  const int q = lane >> 4;        // k-group / row-group selector
  const int r = lane & 15;        // M (A) / N (B) / col (C) index
  const int l0 = blockIdx.x * 128 + wave * 32;

  // A-frag lane base: Wt[t][16m + r][i0 + 8q ...], 16 contiguous bytes
  const unsigned short* abase = wt + (r * CIN + q * 8);
  // B-frag lane base: Xp[b][l0 + 16n + r + tap + 512][i0 + 8q ...]
  const unsigned short* bbase = xp + (size_t)(b * LPAD + l0 + r + PAD_LO) * CIN + q * 8;

  f32x4 acc[4][2] = {};  // [m: o-frag][n: l-frag]

#pragma unroll
  for (int kk = 0; kk < 2 * NTAP; ++kk) {
    const int t = kk >> 1;
    const int i0 = (kk & 1) * 32;
    bf16x8_s bfrag[2], afrag[4];
#pragma unroll
    for (int n = 0; n < 2; ++n)
      bfrag[n] = *(const bf16x8_s*)(bbase + (TAP[t] + 16 * n) * CIN + i0);
#pragma unroll
    for (int m = 0; m < 4; ++m)
      afrag[m] = *(const bf16x8_s*)(abase + (t * COUT + 16 * m) * CIN + i0);
#pragma unroll
    for (int m = 0; m < 4; ++m)
#pragma unroll
      for (int n = 0; n < 2; ++n)
        acc[m][n] = mfma_16x16x32_bf16(afrag[m], bfrag[n], acc[m][n], 0);
  }

  // C/D layout: col = lane&15, row = (lane>>4)*4 + reg
#pragma unroll
  for (int m = 0; m < 4; ++m)
#pragma unroll
    for (int n = 0; n < 2; ++n)
#pragma unroll
      for (int d = 0; d < 4; ++d) {
        const int o = 16 * m + q * 4 + d;
        const int l = l0 + 16 * n + r;
        out[(size_t)(b * COUT + o) * LEN + l] = acc[m][n][d];
      }
}

extern "C" void kernel_launch(void* const* d_in, const int* in_sizes, int n_in,
                              void* d_out, int out_size, void* d_ws, size_t ws_size,
                              hipStream_t stream) {
  const float* x = (const float*)d_in[0];        // [16][64][4096]
  const float* w = (const float*)d_in[1];        // [64][64][32]
  float* out = (float*)d_out;                    // [16][64][4096]

  unsigned short* xp = (unsigned short*)d_ws;                    // 16*4864*64 bf16 = 9.96 MB
  unsigned short* wtp = xp + (size_t)B_ * LPAD * CIN;            // 32*64*64 bf16 = 256 KB

  prep_x<<<dim3(LPAD / 64, B_), 256, 0, stream>>>(x, xp);
  prep_w<<<dim3((NTAP * COUT * CIN) / 256), 256, 0, stream>>>(w, wtp);
  sconv_main<<<dim3(LEN / 128, B_), 256, 0, stream>>>(xp, wtp, out);
}

// Round 2
// 123.550 us; speedup vs baseline: 1.3249x; 1.3249x over previous
//
#include <hip/hip_runtime.h>

// SparseConv1D on MI355X, round 1.
// out[b,o,l] = sum_{t,i} W[o,i,t] * x[b,i,l+tap_t]  (zero outside [0,L))
// = 32 shifted GEMMs, MFMA 16x16x32 bf16.
// R1 changes vs R0 (latency-bound, MfmaUtil 7%):
//  - W reordered FRAGMENT-MAJOR: Wf[kk][m][lane][8] -> A-frag load is one
//    contiguous lane-sequential 1KB block (R0 read 16B per 128B row: half the
//    L2 line wasted, scattered).
//  - Register software pipeline, depth P=4 circular frag buffers;
//    __launch_bounds__(256,2) frees VGPRs (R0 compiler chose 64 regs -> serial
//    load/wait/MFMA loop).
//  - Raw s_barrier every 16 kk keeps the 4 waves lockstep so identical A-frag
//    addresses hit L1 instead of L2.
//  - prep_x stores vectorized (ushort4).

#define B_    16
#define CIN   64
#define COUT  64
#define LEN   4096
#define PAD_LO 512
#define PAD_HI 256
#define LPAD  (LEN + PAD_LO + PAD_HI)   // 4864
#define NTAP  32
#define PIPE  4

typedef float f32x4 __attribute__((ext_vector_type(4)));
typedef short bf16x8_s __attribute__((ext_vector_type(8)));
typedef __bf16 bf16x8_b __attribute__((ext_vector_type(8)));

template <typename V>
static __device__ inline auto mfma_16x16x32_bf16(V a, V b, f32x4 c, int)
    -> decltype(__builtin_amdgcn_mfma_f32_16x16x32_bf16(a, b, c, 0, 0, 0)) {
  return __builtin_amdgcn_mfma_f32_16x16x32_bf16(a, b, c, 0, 0, 0);
}
template <typename V>
static __device__ inline f32x4 mfma_16x16x32_bf16(V a, V b, f32x4 c, long) {
  return __builtin_amdgcn_mfma_f32_16x16x32_bf16(
      __builtin_bit_cast(bf16x8_b, a), __builtin_bit_cast(bf16x8_b, b), c, 0, 0, 0);
}

static __device__ inline unsigned short f32_to_bf16_rne(float f) {
  unsigned int u = __builtin_bit_cast(unsigned int, f);
  u += 0x7fffu + ((u >> 16) & 1u);
  return (unsigned short)(u >> 16);
}

// ---------------- prep: x[b][i][l] fp32 -> Xp[b][lp][i] bf16 (padded) -------------
__global__ __launch_bounds__(256) void prep_x(const float* __restrict__ x,
                                              unsigned short* __restrict__ xp) {
  __shared__ float tile[64][65];
  const int b = blockIdx.y;
  const int lp0 = blockIdx.x * 64;
  const int tid = threadIdx.x;
  const bool data = (lp0 >= PAD_LO) && (lp0 < PAD_LO + LEN);
  if (data) {
    const int l0 = lp0 - PAD_LO;
#pragma unroll
    for (int it = 0; it < 16; ++it) {
      const int p = tid + it * 256;
      const int il = p >> 6, ll = p & 63;            // lanes -> consecutive l (coalesced)
      tile[ll][il] = x[(size_t)(b * CIN + il) * LEN + l0 + ll];
    }
  }
  __syncthreads();
#pragma unroll
  for (int it = 0; it < 4; ++it) {
    const int p = tid + it * 256;
    const int ll = p >> 4, i4 = (p & 15) * 4;        // lanes -> consecutive i (8B stores)
    ushort4 v = {0, 0, 0, 0};
    if (data) {
      v.x = f32_to_bf16_rne(tile[ll][i4 + 0]);
      v.y = f32_to_bf16_rne(tile[ll][i4 + 1]);
      v.z = f32_to_bf16_rne(tile[ll][i4 + 2]);
      v.w = f32_to_bf16_rne(tile[ll][i4 + 3]);
    }
    *(ushort4*)(xp + (size_t)(b * LPAD + lp0 + ll) * CIN + i4) = v;
  }
}

// -------- prep: w[o][i][t] fp32 -> fragment-major Wf[kk][m][lane][8] bf16 --------
// kk = t*2 + c (c = i-half), m = o-frag, lane = q*16+r, elem j:
//   value = W[o=16m+r][i=c*32+q*8+j][t]
__global__ __launch_bounds__(256) void prep_w(const float* __restrict__ w,
                                              unsigned short* __restrict__ wf) {
  const int e = blockIdx.x * 256 + threadIdx.x;     // < 64*4*64*8 = 131072
  const int j = e & 7;
  const int lane = (e >> 3) & 63;
  const int m = (e >> 9) & 3;
  const int kk = e >> 11;
  const int t = kk >> 1, c = kk & 1;
  const int q = lane >> 4, r = lane & 15;
  const int o = 16 * m + r;
  const int i = c * 32 + q * 8 + j;
  wf[e] = f32_to_bf16_rne(w[(size_t)(o * CIN + i) * NTAP + t]);
}

// ---------------- main: 32 shifted GEMMs, software-pipelined ---------------------
__global__ __launch_bounds__(256, 2) void sconv_main(const unsigned short* __restrict__ xp,
                                                     const unsigned short* __restrict__ wf,
                                                     float* __restrict__ out) {
  constexpr int TAP[NTAP] = {-512, -256, -128, -96, -64, -48, -32, -24, -16, -12, -8,
                             -6,   -4,   -3,   -2,  -1,  0,   1,   2,   3,   4,  6,
                             8,    12,   16,   24,  32,  48,  64,  96,  128, 256};
  const int b = blockIdx.y;
  const int wave = threadIdx.x >> 6;
  const int lane = threadIdx.x & 63;
  const int q = lane >> 4;
  const int r = lane & 15;
  const int l0 = blockIdx.x * 128 + wave * 32;

  // A: fragment-major, contiguous per (kk,m): element index (kk*4+m)*512 + lane*8
  const bf16x8_s* abase = (const bf16x8_s*)wf + lane;   // + (kk*4+m)*64
  // B: Xp[b][l0 + 16n + r + tap + PAD_LO][c*32 + q*8 ...]
  const unsigned short* bbase = xp + (size_t)(b * LPAD + l0 + r + PAD_LO) * CIN + q * 8;

  f32x4 acc[4][2] = {};
  bf16x8_s af[PIPE][4], bf_[PIPE][2];

#pragma unroll
  for (int kk = 0; kk < PIPE; ++kk) {
    const int t = kk >> 1, c = kk & 1;
#pragma unroll
    for (int m = 0; m < 4; ++m) af[kk][m] = abase[(kk * 4 + m) * 64];
#pragma unroll
    for (int n = 0; n < 2; ++n)
      bf_[kk][n] = *(const bf16x8_s*)(bbase + (TAP[t] + 16 * n) * CIN + c * 32);
  }

#pragma unroll
  for (int kk = 0; kk < 2 * NTAP; ++kk) {
    const int slot = kk & (PIPE - 1);
#pragma unroll
    for (int m = 0; m < 4; ++m)
#pragma unroll
      for (int n = 0; n < 2; ++n)
        acc[m][n] = mfma_16x16x32_bf16(af[slot][m], bf_[slot][n], acc[m][n], 0);
    if (kk + PIPE < 2 * NTAP) {
      const int kn = kk + PIPE;
      const int t = kn >> 1, c = kn & 1;
#pragma unroll
      for (int m = 0; m < 4; ++m) af[slot][m] = abase[(kn * 4 + m) * 64];
#pragma unroll
      for (int n = 0; n < 2; ++n)
        bf_[slot][n] = *(const bf16x8_s*)(bbase + (TAP[t] + 16 * n) * CIN + c * 32);
    }
    // keep the block's waves lockstep so identical A-frag streams hit L1
    if ((kk & 15) == 15 && kk != 2 * NTAP - 1) __builtin_amdgcn_s_barrier();
  }

  // C/D layout: col(l) = lane&15, row(o) = (lane>>4)*4 + reg
#pragma unroll
  for (int m = 0; m < 4; ++m)
#pragma unroll
    for (int n = 0; n < 2; ++n)
#pragma unroll
      for (int d = 0; d < 4; ++d) {
        const int o = 16 * m + q * 4 + d;
        const int l = l0 + 16 * n + r;
        out[(size_t)(b * COUT + o) * LEN + l] = acc[m][n][d];
      }
}

extern "C" void kernel_launch(void* const* d_in, const int* in_sizes, int n_in,
                              void* d_out, int out_size, void* d_ws, size_t ws_size,
                              hipStream_t stream) {
  const float* x = (const float*)d_in[0];        // [16][64][4096]
  const float* w = (const float*)d_in[1];        // [64][64][32]
  float* out = (float*)d_out;                    // [16][64][4096]

  unsigned short* xp = (unsigned short*)d_ws;                    // 16*4864*64 bf16 = 9.96 MB
  unsigned short* wfp = xp + (size_t)B_ * LPAD * CIN;            // 64*4*64*8 bf16 = 256 KB

  prep_x<<<dim3(LPAD / 64, B_), 256, 0, stream>>>(x, xp);
  prep_w<<<dim3((2 * NTAP * 4 * 64 * 8) / 256), 256, 0, stream>>>(w, wfp);
  sconv_main<<<dim3(LEN / 128, B_), 256, 0, stream>>>(xp, wfp, out);
}

// Round 3
// 94.047 us; speedup vs baseline: 1.7405x; 1.3137x over previous
//
#include <hip/hip_runtime.h>

// SparseConv1D on MI355X, round 2.
// out[b,o,l] = sum_{t,i} W[o,i,t] * x[b,i,l+tap_t] = 32 shifted GEMMs (MFMA 16x16x32 bf16).
// R2: LDS double-buffer + global_load_lds(16B) staging issued ONE TAP AHEAD of the
// barrier (R1's register pipeline was collapsed by the compiler: VGPR=68, loads
// serialized, MfmaUtil 11%). Per block (64o x 128l): stage X-window 16KB + W_t 8KB
// per tap; 48KB LDS dbuf; wave tile 32o x 64l (m2 n4 c2). B ds_reads XOR-swizzled
// to the 8-lane/bank b128 floor. One barrier per tap.

#define B_    16
#define CIN   64
#define COUT  64
#define LEN   4096
#define PAD_LO 512
#define PAD_HI 256
#define LPAD  (LEN + PAD_LO + PAD_HI)   // 4864
#define NTAP  32

typedef float f32x4 __attribute__((ext_vector_type(4)));
typedef short bf16x8_s __attribute__((ext_vector_type(8)));
typedef __bf16 bf16x8_b __attribute__((ext_vector_type(8)));
typedef unsigned short u16x8 __attribute__((ext_vector_type(8)));

template <typename V>
static __device__ inline auto mfma_16x16x32_bf16(V a, V b, f32x4 c, int)
    -> decltype(__builtin_amdgcn_mfma_f32_16x16x32_bf16(a, b, c, 0, 0, 0)) {
  return __builtin_amdgcn_mfma_f32_16x16x32_bf16(a, b, c, 0, 0, 0);
}
template <typename V>
static __device__ inline f32x4 mfma_16x16x32_bf16(V a, V b, f32x4 c, long) {
  return __builtin_amdgcn_mfma_f32_16x16x32_bf16(
      __builtin_bit_cast(bf16x8_b, a), __builtin_bit_cast(bf16x8_b, b), c, 0, 0, 0);
}

static __device__ inline unsigned short f32_to_bf16_rne(float f) {
  unsigned int u = __builtin_bit_cast(unsigned int, f);
  u += 0x7fffu + ((u >> 16) & 1u);
  return (unsigned short)(u >> 16);
}

// async 16B/lane global->LDS; lds dest must be the wave-uniform base (HW adds lane*16)
static __device__ inline void async_copy16(const void* g, void* l) {
  __builtin_amdgcn_global_load_lds((const __attribute__((address_space(1))) unsigned int*)g,
                                   (__attribute__((address_space(3))) unsigned int*)l, 16, 0, 0);
}

// ---------------- prep: x[b][i][l] fp32 -> Xp[b][lp][i] bf16 (padded) -------------
__global__ __launch_bounds__(256) void prep_x(const float* __restrict__ x,
                                              unsigned short* __restrict__ xp) {
  __shared__ float tile[64][65];
  const int b = blockIdx.y;
  const int lp0 = blockIdx.x * 64;
  const int tid = threadIdx.x;
  const bool data = (lp0 >= PAD_LO) && (lp0 < PAD_LO + LEN);
  if (data) {
    const int l0 = lp0 - PAD_LO;
#pragma unroll
    for (int it = 0; it < 4; ++it) {
      const int pidx = it * 256 + tid;
      const int il = pidx >> 4;          // channel
      const int lq = (pidx & 15) * 4;    // 4 consecutive l
      const float4 v = *(const float4*)&x[(size_t)(b * CIN + il) * LEN + l0 + lq];
      tile[lq + 0][il] = v.x;
      tile[lq + 1][il] = v.y;
      tile[lq + 2][il] = v.z;
      tile[lq + 3][il] = v.w;
    }
  }
  __syncthreads();
#pragma unroll
  for (int it = 0; it < 2; ++it) {
    const int pidx = it * 256 + tid;
    const int ll = pidx >> 3;
    const int i8 = (pidx & 7) * 8;
    u16x8 v = {0, 0, 0, 0, 0, 0, 0, 0};
    if (data) {
#pragma unroll
      for (int j = 0; j < 8; ++j) v[j] = f32_to_bf16_rne(tile[ll][i8 + j]);
    }
    *(u16x8*)&xp[(size_t)(b * LPAD + lp0 + ll) * CIN + i8] = v;
  }
}

// ------ prep: w[o][i][t] fp32 -> Wf[t][c][m][lane][8] bf16 (frag-major, 8KB/tap) ---
// A-frag content: W[o = 16m + (lane&15)][i = c*32 + (lane>>4)*8 + j][t]
__global__ __launch_bounds__(256) void prep_w(const float* __restrict__ w,
                                              unsigned short* __restrict__ wf) {
  const int e = blockIdx.x * 256 + threadIdx.x;  // < 32*2*4*64*8 = 131072
  const int j = e & 7;
  const int lane = (e >> 3) & 63;
  const int m = (e >> 9) & 3;
  const int c = (e >> 11) & 1;
  const int t = e >> 12;
  const int q = lane >> 4, r = lane & 15;
  const int o = m * 16 + r;
  const int i = c * 32 + q * 8 + j;
  wf[e] = f32_to_bf16_rne(w[(size_t)(o * CIN + i) * NTAP + t]);
}

// ---------------- main: LDS-dbuf staged, one barrier per tap ---------------------
__global__ __launch_bounds__(256, 2) void sconv_main(const unsigned short* __restrict__ xp,
                                                     const unsigned short* __restrict__ wf,
                                                     float* __restrict__ out) {
  constexpr int TAP[NTAP] = {-512, -256, -128, -96, -64, -48, -32, -24, -16, -12, -8,
                             -6,   -4,   -3,   -2,  -1,  0,   1,   2,   3,   4,  6,
                             8,    12,   16,   24,  32,  48,  64,  96,  128, 256};
  __shared__ alignas(16) char smem[2][24576];  // [0,16384): B 128-row window; [16384,): W_t

  const int b = blockIdx.y;
  const int l0 = blockIdx.x * 128;
  const int tid = threadIdx.x;
  const int wave = tid >> 6, lane = tid & 63;
  const int q = lane >> 4, r = lane & 15;
  const int oh = wave & 1, lh = wave >> 1;   // wave tile: o in [32oh,32oh+32), l in [l0+64lh, +64)

  // B staging source offsets (bytes, relative to window base), XOR-swizzled:
  // LDS chunk s holds global chunk (row = s>>3, (s&7) ^ (row&7))
  int boff[4];
#pragma unroll
  for (int it = 0; it < 4; ++it) {
    const int s = it * 256 + tid;
    const int row = s >> 3, ch = s & 7;
    boff[it] = (row * 8 + (ch ^ (row & 7))) * 16;
  }

  const char* xbase = (const char*)xp + (size_t)(b * LPAD + l0 + PAD_LO) * (CIN * 2);
  const char* wbase = (const char*)wf;

  auto stage = [&](int t, int p) {
    const char* win = xbase + TAP[t] * (CIN * 2);
#pragma unroll
    for (int it = 0; it < 4; ++it)
      async_copy16(win + boff[it], &smem[p][(it * 256 + wave * 64) * 16]);
    const char* wsrc = wbase + t * 8192;
#pragma unroll
    for (int it = 0; it < 2; ++it)
      async_copy16(wsrc + (it * 256 + wave * 64 + lane) * 16,
                   &smem[p][16384 + (it * 256 + wave * 64) * 16]);
  };

  f32x4 acc[2][4] = {};

  stage(0, 0);

#pragma unroll
  for (int t = 0; t < NTAP; ++t) {
    const int p = t & 1;
    __syncthreads();                       // buf[p] staged (issued one tap ago)
    if (t + 1 < NTAP) stage(t + 1, p ^ 1); // async, stays in flight through compute(t)
    __builtin_amdgcn_sched_barrier(0);     // keep stage loads above the ds_reads
    const char* Bb = smem[p];
    const char* Wb = smem[p] + 16384;
#pragma unroll
    for (int c = 0; c < 2; ++c) {
      bf16x8_s A[2], Bf[4];
#pragma unroll
      for (int m = 0; m < 2; ++m)
        A[m] = *(const bf16x8_s*)(Wb + (c * 256 + (oh * 2 + m) * 64 + lane) * 16);
#pragma unroll
      for (int n = 0; n < 4; ++n) {
        const int row = lh * 64 + n * 16 + r;
        Bf[n] = *(const bf16x8_s*)(Bb + (row * 8 + ((c * 4 + q) ^ (r & 7))) * 16);
      }
#pragma unroll
      for (int m = 0; m < 2; ++m)
#pragma unroll
        for (int n = 0; n < 4; ++n)
          acc[m][n] = mfma_16x16x32_bf16(A[m], Bf[n], acc[m][n], 0);
    }
  }

  // C/D layout (verified R0/R1): col(l) = lane&15, row(o) = (lane>>4)*4 + reg
#pragma unroll
  for (int m = 0; m < 2; ++m)
#pragma unroll
    for (int n = 0; n < 4; ++n)
#pragma unroll
      for (int d = 0; d < 4; ++d) {
        const int o = oh * 32 + m * 16 + q * 4 + d;
        const int l = l0 + lh * 64 + n * 16 + r;
        out[(size_t)(b * COUT + o) * LEN + l] = acc[m][n][d];
      }
}

extern "C" void kernel_launch(void* const* d_in, const int* in_sizes, int n_in,
                              void* d_out, int out_size, void* d_ws, size_t ws_size,
                              hipStream_t stream) {
  const float* x = (const float*)d_in[0];        // [16][64][4096]
  const float* w = (const float*)d_in[1];        // [64][64][32]
  float* out = (float*)d_out;                    // [16][64][4096]

  unsigned short* xp = (unsigned short*)d_ws;                    // 16*4864*64 bf16 = 9.96 MB
  unsigned short* wfp = xp + (size_t)B_ * LPAD * CIN;            // 32*2*4*64*8 bf16 = 256 KB

  prep_x<<<dim3(LPAD / 64, B_), 256, 0, stream>>>(x, xp);
  prep_w<<<dim3((NTAP * 2 * 4 * 64 * 8) / 256), 256, 0, stream>>>(w, wfp);
  sconv_main<<<dim3(LEN / 128, B_), 256, 0, stream>>>(xp, wfp, out);
}